// Round 1
// baseline (3758.740 us; speedup 1.0000x reference)
//
#include <hip/hip_runtime.h>
#include <hip/hip_bf16.h>

#define T_LEN 32768
#define B_N   4
#define RC    32
#define DC    32
#define SC    256
#define OUTC  256
#define NL    40

// ---------- helpers ----------
__device__ __forceinline__ unsigned short f2bf_bits(float f) {
    __hip_bfloat16 b = __float2bfloat16(f);
    unsigned short u;
    __builtin_memcpy(&u, &b, 2);
    return u;
}
__device__ __forceinline__ unsigned pack2(float a, float b) {
    return (unsigned)f2bf_bits(a) | ((unsigned)f2bf_bits(b) << 16);
}
__device__ __forceinline__ float4 bf4_to_f4(uint2 v) {
    float4 r;
    r.x = __uint_as_float((v.x & 0xFFFFu) << 16);
    r.y = __uint_as_float(v.x & 0xFFFF0000u);
    r.z = __uint_as_float((v.y & 0xFFFFu) << 16);
    r.w = __uint_as_float(v.y & 0xFFFF0000u);
    return r;
}

// ---------- start conv: h0[b,c,t] = W_start[c]*x[b,t] + b_start[c] ----------
__global__ __launch_bounds__(256) void k_start(const float* __restrict__ x,
                                               const float* __restrict__ Wst,
                                               const float* __restrict__ bst,
                                               float* __restrict__ h0) {
    int g = blockIdx.x * 256 + threadIdx.x;      // b*T + t
    int b = g >> 15, t = g & (T_LEN - 1);
    float xv = x[g];
#pragma unroll
    for (int c = 0; c < RC; ++c) {
        h0[((b * RC + c) << 15) + t] = Wst[c] * xv + bst[c];
    }
}

// ---------- one WaveNet layer ----------
// z = tanh(Wd[:,:,1]@h + Wd[:,:,0]@h_shift + bd); h' = h + Wr@z + br
// writes h' (f32) and bf16 copy into hist slot
__global__ __launch_bounds__(256) void k_layer(const float* __restrict__ hin,
                                               float* __restrict__ hout,
                                               __hip_bfloat16* __restrict__ hist,
                                               const float* __restrict__ Wd,  // [DC][RC][2]
                                               const float* __restrict__ bd,  // [DC]
                                               const float* __restrict__ Wr,  // [RC][DC]
                                               const float* __restrict__ br,  // [RC]
                                               int d) {
    int g = blockIdx.x * 256 + threadIdx.x;
    int b = g >> 15, t = g & (T_LEN - 1);
    const float* hb = hin + ((b * RC) << 15) + t;

    float hc[RC], hs[RC];
#pragma unroll
    for (int c = 0; c < RC; ++c) hc[c] = hb[c << 15];
    if (t >= d) {
#pragma unroll
        for (int c = 0; c < RC; ++c) hs[c] = hb[(c << 15) - d];
    } else {
#pragma unroll
        for (int c = 0; c < RC; ++c) hs[c] = 0.f;
    }

    const float2* wd2 = (const float2*)Wd;   // wd2[o*RC+c] = {k0, k1}
    float z[DC];
#pragma unroll 4
    for (int o = 0; o < DC; ++o) {
        float acc = bd[o];
#pragma unroll
        for (int c = 0; c < RC; ++c) {
            float2 w = wd2[o * RC + c];
            acc += w.y * hc[c] + w.x * hs[c];
        }
        z[o] = tanhf(acc);
    }
#pragma unroll 4
    for (int o = 0; o < RC; ++o) {
        float acc = br[o];
#pragma unroll
        for (int c = 0; c < DC; ++c) acc += Wr[o * DC + c] * z[c];
        float hn = hc[o] + acc;
        int idx = ((b * RC + o) << 15) + t;
        hout[idx] = hn;
        hist[idx] = __float2bfloat16(hn);
    }
}

// ---------- skip matmul: sk[b,oc,t] = relu( sum_k WsAll[oc,k]*hist[k,b,t] + bs_sum[oc] ) ----------
// k = i*32 + c ; hist laid out [i][b][c][t] ; output bf16
__global__ __launch_bounds__(256) void k_skip(const __hip_bfloat16* __restrict__ hist,
                                              const float* __restrict__ Ws,  // [NL][SC][RC]
                                              const float* __restrict__ bs,  // [NL][SC]
                                              __hip_bfloat16* __restrict__ sk) {
    __shared__ float Wl[32][132];
    __shared__ float Hl[32][132];
    int tid = threadIdx.x;
    int tx = tid & 15;   // t micro-tile: 8 consecutive t
    int ty = tid >> 4;   // oc micro-tile: 8 consecutive oc
    int t0 = blockIdx.x * 128;
    int oc0 = blockIdx.y * 128;
    int b = blockIdx.z;

    float acc[8][8];
#pragma unroll
    for (int i = 0; i < 8; ++i)
#pragma unroll
        for (int j = 0; j < 8; ++j) acc[i][j] = 0.f;

    for (int i = 0; i < NL; ++i) {
        // stage Ws chunk: Wl[c][oc] = Ws[(i*SC+oc0+oc)*RC + c]
        for (int idx = tid; idx < 1024; idx += 256) {
            int oc = idx >> 3, cq = idx & 7;
            float4 w = *(const float4*)&Ws[(i * SC + oc0 + oc) * RC + cq * 4];
            Wl[cq * 4 + 0][oc] = w.x;
            Wl[cq * 4 + 1][oc] = w.y;
            Wl[cq * 4 + 2][oc] = w.z;
            Wl[cq * 4 + 3][oc] = w.w;
        }
        // stage hist chunk: Hl[c][tt] = hist[((i*B+b)*RC+c)*T + t0+tt]
        for (int idx = tid; idx < 1024; idx += 256) {
            int c = idx >> 5, tq = idx & 31;
            uint2 v = *(const uint2*)&hist[(size_t)((i * B_N + b) * RC + c) * T_LEN + t0 + tq * 4];
            *(float4*)&Hl[c][tq * 4] = bf4_to_f4(v);
        }
        __syncthreads();
#pragma unroll 8
        for (int k = 0; k < 32; ++k) {
            float4 w0 = *(const float4*)&Wl[k][ty * 8];
            float4 w1 = *(const float4*)&Wl[k][ty * 8 + 4];
            float4 h0 = *(const float4*)&Hl[k][tx * 8];
            float4 h1 = *(const float4*)&Hl[k][tx * 8 + 4];
            float wv[8] = {w0.x, w0.y, w0.z, w0.w, w1.x, w1.y, w1.z, w1.w};
            float hv[8] = {h0.x, h0.y, h0.z, h0.w, h1.x, h1.y, h1.z, h1.w};
#pragma unroll
            for (int jo = 0; jo < 8; ++jo)
#pragma unroll
                for (int jt = 0; jt < 8; ++jt) acc[jo][jt] += wv[jo] * hv[jt];
        }
        __syncthreads();
    }

    // bias sum over layers, relu, bf16 store
#pragma unroll
    for (int jo = 0; jo < 8; ++jo) {
        int oc = oc0 + ty * 8 + jo;
        float bsum = 0.f;
        for (int i = 0; i < NL; ++i) bsum += bs[i * SC + oc];
        float v[8];
#pragma unroll
        for (int jt = 0; jt < 8; ++jt) v[jt] = fmaxf(acc[jo][jt] + bsum, 0.f);
        uint4 u;
        u.x = pack2(v[0], v[1]);
        u.y = pack2(v[2], v[3]);
        u.z = pack2(v[4], v[5]);
        u.w = pack2(v[6], v[7]);
        *(uint4*)&sk[(size_t)(b * SC + oc) * T_LEN + t0 + tx * 8] = u;
    }
}

// ---------- final conv: out[b,o,t] = sum_c Wf[o,c]*sk[b,c,t] + bf[o] ----------
__global__ __launch_bounds__(256) void k_final(const __hip_bfloat16* __restrict__ sk,
                                               const float* __restrict__ Wf,  // [OUTC][SC]
                                               const float* __restrict__ bfv, // [OUTC]
                                               float* __restrict__ outp) {
    __shared__ float Wl[32][132];
    __shared__ float Hl[32][132];
    int tid = threadIdx.x;
    int tx = tid & 15;
    int ty = tid >> 4;
    int t0 = blockIdx.x * 128;
    int oc0 = blockIdx.y * 128;
    int b = blockIdx.z;

    float acc[8][8];
#pragma unroll
    for (int i = 0; i < 8; ++i)
#pragma unroll
        for (int j = 0; j < 8; ++j) acc[i][j] = 0.f;

    for (int kk = 0; kk < SC / 32; ++kk) {
        for (int idx = tid; idx < 1024; idx += 256) {
            int oc = idx >> 3, cq = idx & 7;
            float4 w = *(const float4*)&Wf[(oc0 + oc) * SC + kk * 32 + cq * 4];
            Wl[cq * 4 + 0][oc] = w.x;
            Wl[cq * 4 + 1][oc] = w.y;
            Wl[cq * 4 + 2][oc] = w.z;
            Wl[cq * 4 + 3][oc] = w.w;
        }
        for (int idx = tid; idx < 1024; idx += 256) {
            int c = idx >> 5, tq = idx & 31;
            uint2 v = *(const uint2*)&sk[(size_t)(b * SC + kk * 32 + c) * T_LEN + t0 + tq * 4];
            *(float4*)&Hl[c][tq * 4] = bf4_to_f4(v);
        }
        __syncthreads();
#pragma unroll 8
        for (int k = 0; k < 32; ++k) {
            float4 w0 = *(const float4*)&Wl[k][ty * 8];
            float4 w1 = *(const float4*)&Wl[k][ty * 8 + 4];
            float4 h0 = *(const float4*)&Hl[k][tx * 8];
            float4 h1 = *(const float4*)&Hl[k][tx * 8 + 4];
            float wv[8] = {w0.x, w0.y, w0.z, w0.w, w1.x, w1.y, w1.z, w1.w};
            float hv[8] = {h0.x, h0.y, h0.z, h0.w, h1.x, h1.y, h1.z, h1.w};
#pragma unroll
            for (int jo = 0; jo < 8; ++jo)
#pragma unroll
                for (int jt = 0; jt < 8; ++jt) acc[jo][jt] += wv[jo] * hv[jt];
        }
        __syncthreads();
    }

#pragma unroll
    for (int jo = 0; jo < 8; ++jo) {
        int oc = oc0 + ty * 8 + jo;
        float bias = bfv[oc];
        float4 r0, r1;
        r0.x = acc[jo][0] + bias; r0.y = acc[jo][1] + bias;
        r0.z = acc[jo][2] + bias; r0.w = acc[jo][3] + bias;
        r1.x = acc[jo][4] + bias; r1.y = acc[jo][5] + bias;
        r1.z = acc[jo][6] + bias; r1.w = acc[jo][7] + bias;
        size_t o = (size_t)(b * OUTC + oc) * T_LEN + t0 + tx * 8;
        *(float4*)&outp[o] = r0;
        *(float4*)&outp[o + 4] = r1;
    }
}

extern "C" void kernel_launch(void* const* d_in, const int* in_sizes, int n_in,
                              void* d_out, int out_size, void* d_ws, size_t ws_size,
                              hipStream_t stream) {
    const float* x       = (const float*)d_in[0];
    const float* W_start = (const float*)d_in[1];
    const float* b_start = (const float*)d_in[2];
    const float* Wd      = (const float*)d_in[3];
    const float* bd      = (const float*)d_in[4];
    const float* Wr      = (const float*)d_in[5];
    const float* br      = (const float*)d_in[6];
    const float* Ws      = (const float*)d_in[7];
    const float* bs      = (const float*)d_in[8];
    const float* Wf      = (const float*)d_in[9];
    const float* bfv     = (const float*)d_in[10];

    char* wsb = (char*)d_ws;
    const size_t hist_bytes = (size_t)NL * B_N * RC * T_LEN * 2;  // 320 MB
    __hip_bfloat16* hist = (__hip_bfloat16*)wsb;
    float* ping = (float*)(wsb + hist_bytes);
    float* pong = (float*)(wsb + hist_bytes + (size_t)B_N * RC * T_LEN * 4);
    // sk reuses the ping/pong region after pass A (extends 32MB beyond it)
    __hip_bfloat16* sk = (__hip_bfloat16*)(wsb + hist_bytes);

    k_start<<<512, 256, 0, stream>>>(x, W_start, b_start, ping);

    float* hin = ping;
    float* hout = pong;
    for (int i = 0; i < NL; ++i) {
        int d = 1 << (i % 10);
        k_layer<<<512, 256, 0, stream>>>(hin, hout,
                                         hist + (size_t)i * B_N * RC * T_LEN,
                                         Wd + (size_t)i * DC * RC * 2, bd + i * DC,
                                         Wr + (size_t)i * RC * DC, br + i * RC, d);
        float* tmp = hin; hin = hout; hout = tmp;
    }

    dim3 g1(T_LEN / 128, SC / 128, B_N);
    k_skip<<<g1, 256, 0, stream>>>(hist, Ws, bs, sk);

    dim3 g2(T_LEN / 128, OUTC / 128, B_N);
    k_final<<<g2, 256, 0, stream>>>(sk, Wf, bfv, (float*)d_out);
}

// Round 2
// 2383.642 us; speedup vs baseline: 1.5769x; 1.5769x over previous
//
#include <hip/hip_runtime.h>
#include <hip/hip_bf16.h>

#define T_LEN 32768
#define B_N   4
#define RC    32
#define DC    32
#define SC    256
#define OUTC  256
#define NL    40
#define KTOT  (NL * RC)   // 1280

typedef float f32x4 __attribute__((ext_vector_type(4)));
typedef short bf16x8 __attribute__((ext_vector_type(8)));

// ---------- helpers ----------
__device__ __forceinline__ unsigned short f2bf_bits(float f) {
    __hip_bfloat16 b = __float2bfloat16(f);
    unsigned short u;
    __builtin_memcpy(&u, &b, 2);
    return u;
}
__device__ __forceinline__ unsigned pack2(float a, float b) {
    return (unsigned)f2bf_bits(a) | ((unsigned)f2bf_bits(b) << 16);
}
__device__ __forceinline__ float ftanh(float x) {
    float e = __expf(2.f * x);
    return 1.f - 2.f / (e + 1.f);
}

// ---------- prep: bf16 weight packs + bias sum ----------
// Wsk[oc][k=i*32+c] = Ws[i][oc][c] ; Wfk[o][c] = Wf[o][c] ; bs_sum[oc] = sum_i bs[i][oc]
__global__ __launch_bounds__(256) void k_prep(const float* __restrict__ Ws,
                                              const float* __restrict__ Wf,
                                              const float* __restrict__ bs,
                                              unsigned short* __restrict__ Wsk,
                                              unsigned short* __restrict__ Wfk,
                                              float* __restrict__ bs_sum) {
    int g = blockIdx.x * 256 + threadIdx.x;
    if (g < SC * KTOT) {
        int oc = g / KTOT, k = g - oc * KTOT;
        int i = k >> 5, c = k & 31;
        Wsk[g] = f2bf_bits(Ws[(i * SC + oc) * RC + c]);
    } else if (g < SC * KTOT + OUTC * SC) {
        int j = g - SC * KTOT;
        Wfk[j] = f2bf_bits(Wf[j]);
    } else if (g < SC * KTOT + OUTC * SC + SC) {
        int oc = g - SC * KTOT - OUTC * SC;
        float s = 0.f;
        for (int i = 0; i < NL; ++i) s += bs[i * SC + oc];
        bs_sum[oc] = s;
    }
}

// ---------- start conv: h0[bt][c] = W_start[c]*x[bt] + b_start[c] (channel-fast) ----------
__global__ __launch_bounds__(256) void k_start(const float* __restrict__ x,
                                               const float* __restrict__ Wst,
                                               const float* __restrict__ bst,
                                               float* __restrict__ h0) {
    int g = blockIdx.x * 256 + threadIdx.x;   // bt
    float xv = x[g];
    float* op = h0 + (size_t)g * RC;
#pragma unroll
    for (int q = 0; q < 8; ++q) {
        float4 v;
        v.x = Wst[q * 4 + 0] * xv + bst[q * 4 + 0];
        v.y = Wst[q * 4 + 1] * xv + bst[q * 4 + 1];
        v.z = Wst[q * 4 + 2] * xv + bst[q * 4 + 2];
        v.w = Wst[q * 4 + 3] * xv + bst[q * 4 + 3];
        *(float4*)&op[q * 4] = v;
    }
}

// ---------- one WaveNet layer (channel-fast layout) ----------
__global__ __launch_bounds__(256) void k_layer(const float* __restrict__ hin,
                                               float* __restrict__ hout,
                                               unsigned short* __restrict__ histslot,
                                               const float* __restrict__ Wd,  // [DC][RC][2]
                                               const float* __restrict__ bd,
                                               const float* __restrict__ Wr,  // [RC][DC]
                                               const float* __restrict__ br,
                                               int d) {
    int g = blockIdx.x * 256 + threadIdx.x;   // bt
    int t = g & (T_LEN - 1);
    const float* hp = hin + (size_t)g * RC;

    float hc[RC];
#pragma unroll
    for (int q = 0; q < 8; ++q) *(float4*)&hc[q * 4] = *(const float4*)&hp[q * 4];
    float hs[RC];
    if (t >= d) {
        const float* sp = hp - (size_t)d * RC;
#pragma unroll
        for (int q = 0; q < 8; ++q) *(float4*)&hs[q * 4] = *(const float4*)&sp[q * 4];
    } else {
#pragma unroll
        for (int q = 0; q < RC; ++q) hs[q] = 0.f;
    }

    float z[DC];
#pragma unroll 2
    for (int o = 0; o < DC; ++o) {
        float acc = bd[o];
#pragma unroll
        for (int c = 0; c < RC; ++c) {
            acc = fmaf(Wd[(o * RC + c) * 2 + 1], hc[c], acc);
            acc = fmaf(Wd[(o * RC + c) * 2 + 0], hs[c], acc);
        }
        z[o] = ftanh(acc);
    }

    float hn[RC];
#pragma unroll 2
    for (int o = 0; o < RC; ++o) {
        float acc = br[o];
#pragma unroll
        for (int c = 0; c < DC; ++c) acc = fmaf(Wr[o * DC + c], z[c], acc);
        hn[o] = hc[o] + acc;
    }

    float* op = hout + (size_t)g * RC;
#pragma unroll
    for (int q = 0; q < 8; ++q) *(float4*)&op[q * 4] = *(const float4*)&hn[q * 4];

    unsigned u[16];
#pragma unroll
    for (int q = 0; q < 16; ++q) u[q] = pack2(hn[2 * q], hn[2 * q + 1]);
    unsigned short* hsl = histslot + (size_t)g * RC;
#pragma unroll
    for (int q = 0; q < 4; ++q) *(uint4*)&hsl[q * 8] = *(uint4*)&u[q * 4];
}

// ---------- skip GEMM (MFMA): sk[bt][oc] = relu( Wsk[oc][:] @ hist[:][bt] + bs_sum[oc] ), bf16 out ----------
// hist[i][b][t][c] bf16 ; no LDS, no barriers. Block = 4 waves; wave wq owns oc in [wq*64, wq*64+64).
__global__ __launch_bounds__(256) void k_skip(const unsigned short* __restrict__ hist,
                                              const unsigned short* __restrict__ Wsk,
                                              const float* __restrict__ bs_sum,
                                              unsigned short* __restrict__ sk) {
    int bt0 = blockIdx.x * 64;
    int lane = threadIdx.x & 63;
    int wq = threadIdx.x >> 6;
    int lr = lane & 15, lg = lane >> 4;
    int ocb = wq * 64;

    f32x4 acc[4][4];
#pragma unroll
    for (int m = 0; m < 4; ++m)
#pragma unroll
        for (int n = 0; n < 4; ++n) acc[m][n] = (f32x4){0.f, 0.f, 0.f, 0.f};

    for (int i = 0; i < NL; ++i) {
        bf16x8 a[4], bb[4];
        const unsigned short* Arow = Wsk + (size_t)(ocb + lr) * KTOT + i * 32 + 8 * lg;
#pragma unroll
        for (int m = 0; m < 4; ++m) a[m] = *(const bf16x8*)(Arow + (size_t)m * 16 * KTOT);
        const unsigned short* Brow = hist + ((size_t)i * B_N * T_LEN + bt0 + lr) * RC + 8 * lg;
#pragma unroll
        for (int n = 0; n < 4; ++n) bb[n] = *(const bf16x8*)(Brow + (size_t)n * 16 * RC);
#pragma unroll
        for (int m = 0; m < 4; ++m)
#pragma unroll
            for (int n = 0; n < 4; ++n)
                acc[m][n] = __builtin_amdgcn_mfma_f32_16x16x32_bf16(a[m], bb[n], acc[m][n], 0, 0, 0);
    }

#pragma unroll
    for (int m = 0; m < 4; ++m) {
        int oc0 = ocb + m * 16 + lg * 4;
        float b0 = bs_sum[oc0], b1 = bs_sum[oc0 + 1], b2 = bs_sum[oc0 + 2], b3 = bs_sum[oc0 + 3];
#pragma unroll
        for (int n = 0; n < 4; ++n) {
            int bt = bt0 + n * 16 + lr;
            f32x4 v = acc[m][n];
            uint2 u;
            u.x = pack2(fmaxf(v[0] + b0, 0.f), fmaxf(v[1] + b1, 0.f));
            u.y = pack2(fmaxf(v[2] + b2, 0.f), fmaxf(v[3] + b3, 0.f));
            *(uint2*)&sk[(size_t)bt * SC + oc0] = u;
        }
    }
}

// ---------- final GEMM (MFMA): out[b][o][t] = Wfk[o][:] @ sk[bt][:] + bf[o], f32 out ----------
__global__ __launch_bounds__(256) void k_final(const unsigned short* __restrict__ sk,
                                               const unsigned short* __restrict__ Wfk,
                                               const float* __restrict__ bfv,
                                               float* __restrict__ outp) {
    int bt0 = blockIdx.x * 64;
    int lane = threadIdx.x & 63;
    int wq = threadIdx.x >> 6;
    int lr = lane & 15, lg = lane >> 4;
    int ob = wq * 64;

    f32x4 acc[4][4];
#pragma unroll
    for (int m = 0; m < 4; ++m)
#pragma unroll
        for (int n = 0; n < 4; ++n) acc[m][n] = (f32x4){0.f, 0.f, 0.f, 0.f};

#pragma unroll
    for (int kk = 0; kk < SC / 32; ++kk) {
        bf16x8 a[4], bb[4];
        const unsigned short* Arow = Wfk + (size_t)(ob + lr) * SC + kk * 32 + 8 * lg;
#pragma unroll
        for (int m = 0; m < 4; ++m) a[m] = *(const bf16x8*)(Arow + (size_t)m * 16 * SC);
        const unsigned short* Brow = sk + (size_t)(bt0 + lr) * SC + kk * 32 + 8 * lg;
#pragma unroll
        for (int n = 0; n < 4; ++n) bb[n] = *(const bf16x8*)(Brow + (size_t)n * 16 * SC);
#pragma unroll
        for (int m = 0; m < 4; ++m)
#pragma unroll
            for (int n = 0; n < 4; ++n)
                acc[m][n] = __builtin_amdgcn_mfma_f32_16x16x32_bf16(a[m], bb[n], acc[m][n], 0, 0, 0);
    }

    int b = bt0 >> 15;
    int t0 = bt0 & (T_LEN - 1);
#pragma unroll
    for (int m = 0; m < 4; ++m) {
        int o0 = ob + m * 16 + lg * 4;
#pragma unroll
        for (int n = 0; n < 4; ++n) {
            int t = t0 + n * 16 + lr;
            f32x4 v = acc[m][n];
#pragma unroll
            for (int r = 0; r < 4; ++r) {
                outp[((size_t)(b * OUTC + o0 + r) << 15) + t] = v[r] + bfv[o0 + r];
            }
        }
    }
}

extern "C" void kernel_launch(void* const* d_in, const int* in_sizes, int n_in,
                              void* d_out, int out_size, void* d_ws, size_t ws_size,
                              hipStream_t stream) {
    const float* x       = (const float*)d_in[0];
    const float* W_start = (const float*)d_in[1];
    const float* b_start = (const float*)d_in[2];
    const float* Wd      = (const float*)d_in[3];
    const float* bd      = (const float*)d_in[4];
    const float* Wr      = (const float*)d_in[5];
    const float* br      = (const float*)d_in[6];
    const float* Ws      = (const float*)d_in[7];
    const float* bs      = (const float*)d_in[8];
    const float* Wf      = (const float*)d_in[9];
    const float* bfv     = (const float*)d_in[10];

    char* wsb = (char*)d_ws;
    // layout: [Wsk 640K][Wfk 128K][bs_sum 1K][hist 320M][sk 64M (ping/pong overlap inside)]
    unsigned short* Wsk    = (unsigned short*)wsb;
    unsigned short* Wfk    = (unsigned short*)(wsb + 655360);
    float*          bs_sum = (float*)(wsb + 655360 + 131072);
    char* base1 = wsb + 655360 + 131072 + 1024;
    unsigned short* hist = (unsigned short*)base1;
    const size_t hist_bytes = (size_t)NL * B_N * T_LEN * RC * 2;   // 335.5 MB
    char* base2 = base1 + hist_bytes;
    unsigned short* sk = (unsigned short*)base2;                   // 67.1 MB
    float* ping = (float*)base2;                                   // 16.8 MB (dead before sk written)
    float* pong = (float*)(base2 + (size_t)B_N * T_LEN * RC * 4);  // 16.8 MB

    const int NBT = B_N * T_LEN;   // 131072

    k_prep<<<(SC * KTOT + OUTC * SC + SC + 255) / 256, 256, 0, stream>>>(Ws, Wf, bs, Wsk, Wfk, bs_sum);
    k_start<<<NBT / 256, 256, 0, stream>>>(x, W_start, b_start, ping);

    float* hin = ping;
    float* hout = pong;
    for (int i = 0; i < NL; ++i) {
        int d = 1 << (i % 10);
        k_layer<<<NBT / 256, 256, 0, stream>>>(hin, hout,
                                               hist + (size_t)i * B_N * T_LEN * RC,
                                               Wd + (size_t)i * DC * RC * 2, bd + i * DC,
                                               Wr + (size_t)i * RC * DC, br + i * RC, d);
        float* tmp = hin; hin = hout; hout = tmp;
    }

    k_skip<<<NBT / 64, 256, 0, stream>>>(hist, Wsk, bs_sum, sk);
    k_final<<<NBT / 64, 256, 0, stream>>>(sk, Wfk, bfv, (float*)d_out);
}

// Round 3
// 653.650 us; speedup vs baseline: 5.7504x; 3.6467x over previous
//
#include <hip/hip_runtime.h>
#include <hip/hip_bf16.h>

#define T_LEN 32768
#define B_N   4
#define RC    32
#define DC    32
#define SC    256
#define OUTC  256
#define NL    40
#define KTOT  (NL * RC)   // 1280
#define NBT   (B_N * T_LEN)

typedef float f32x4 __attribute__((ext_vector_type(4)));
typedef short bf16x8 __attribute__((ext_vector_type(8)));

// ---------- helpers ----------
__device__ __forceinline__ unsigned short f2bf_bits(float f) {
    __hip_bfloat16 b = __float2bfloat16(f);
    unsigned short u;
    __builtin_memcpy(&u, &b, 2);
    return u;
}
__device__ __forceinline__ unsigned pack2(float a, float b) {
    return (unsigned)f2bf_bits(a) | ((unsigned)f2bf_bits(b) << 16);
}
__device__ __forceinline__ float bflo(unsigned u) { return __uint_as_float((u & 0xFFFFu) << 16); }
__device__ __forceinline__ float bfhi(unsigned u) { return __uint_as_float(u & 0xFFFF0000u); }
__device__ __forceinline__ float ftanh(float x) {
    float e = __expf(2.f * x);
    return 1.f - 2.f / (e + 1.f);
}

// ---------- prep: bf16 weight packs + bias sum ----------
// regions: [Wsk SC*KTOT][Wfk OUTC*SC][Wd1k NL*1024][Wd0k NL*1024][Wrk NL*1024][bs_sum SC]
__global__ __launch_bounds__(256) void k_prep(const float* __restrict__ Ws,
                                              const float* __restrict__ Wf,
                                              const float* __restrict__ Wd,
                                              const float* __restrict__ Wr,
                                              const float* __restrict__ bs,
                                              unsigned short* __restrict__ Wsk,
                                              unsigned short* __restrict__ Wfk,
                                              unsigned short* __restrict__ Wd1k,
                                              unsigned short* __restrict__ Wd0k,
                                              unsigned short* __restrict__ Wrk,
                                              float* __restrict__ bs_sum) {
    int g = blockIdx.x * 256 + threadIdx.x;
    if (g < SC * KTOT) {
        int oc = g / KTOT, k = g - oc * KTOT;
        int i = k >> 5, c = k & 31;
        Wsk[g] = f2bf_bits(Ws[(i * SC + oc) * RC + c]);
        return;
    }
    g -= SC * KTOT;
    if (g < OUTC * SC) { Wfk[g] = f2bf_bits(Wf[g]); return; }
    g -= OUTC * SC;
    if (g < NL * 1024) {
        int i = g >> 10, r = g & 1023;
        int o = r >> 5, c = r & 31;
        Wd1k[g] = f2bf_bits(Wd[((i * DC + o) * RC + c) * 2 + 1]);
        return;
    }
    g -= NL * 1024;
    if (g < NL * 1024) {
        int i = g >> 10, r = g & 1023;
        int o = r >> 5, c = r & 31;
        Wd0k[g] = f2bf_bits(Wd[((i * DC + o) * RC + c) * 2 + 0]);
        return;
    }
    g -= NL * 1024;
    if (g < NL * 1024) { Wrk[g] = f2bf_bits(Wr[g]); return; }
    g -= NL * 1024;
    if (g < SC) {
        float s = 0.f;
        for (int i = 0; i < NL; ++i) s += bs[i * SC + g];
        bs_sum[g] = s;
    }
}

// ---------- start conv -> bf16 stream slot 0 ----------
__global__ __launch_bounds__(256) void k_start(const float* __restrict__ x,
                                               const float* __restrict__ Wst,
                                               const float* __restrict__ bst,
                                               unsigned short* __restrict__ h0) {
    int g = blockIdx.x * 256 + threadIdx.x;   // bt
    float xv = x[g];
    unsigned u[16];
#pragma unroll
    for (int q = 0; q < 16; ++q) {
        float a = Wst[2 * q] * xv + bst[2 * q];
        float b = Wst[2 * q + 1] * xv + bst[2 * q + 1];
        u[q] = pack2(a, b);
    }
    unsigned short* op = h0 + (size_t)g * 32;
#pragma unroll
    for (int q = 0; q < 4; ++q) *(uint4*)&op[q * 8] = *(uint4*)&u[q * 4];
}

// ---------- one WaveNet layer: MFMA, bf16 stream ----------
// wave: 32 bt x 32 oc. conv: z = tanh(Wd1@hc + Wd0@hs + bd); res: h' = hc + Wr@z + br
__global__ __launch_bounds__(256, 4) void k_layer(const unsigned short* __restrict__ hprev,
                                                  unsigned short* __restrict__ hnext,
                                                  const unsigned short* __restrict__ Wd1k, // [32][32]
                                                  const unsigned short* __restrict__ Wd0k,
                                                  const unsigned short* __restrict__ Wrk,
                                                  const float* __restrict__ bd,
                                                  const float* __restrict__ br,
                                                  int d) {
    __shared__ unsigned short zbuf[4][32 * 40];   // per-wave [32 bt][40] bf16 (80B rows)
    int lane = threadIdx.x & 63;
    int wq = threadIdx.x >> 6;
    int lr = lane & 15, lg = lane >> 4;
    int btb = blockIdx.x * 128 + wq * 32;
    unsigned short* zp = &zbuf[wq][0];

    // A-frags (weights): row=oc=m*16+lr, k=c=8*lg+j
    bf16x8 wd1[2], wd0[2], wr[2];
#pragma unroll
    for (int m = 0; m < 2; ++m) {
        int ao = (m * 16 + lr) * 32 + 8 * lg;
        wd1[m] = *(const bf16x8*)(Wd1k + ao);
        wd0[m] = *(const bf16x8*)(Wd0k + ao);
        wr[m]  = *(const bf16x8*)(Wrk + ao);
    }

    // B-frags: col=bt=btb+n*16+lr, k=c=8*lg+j ; plus hc at C-layout for residual add
    bf16x8 hc[2], hs[2];
    uint2 hcc[2][2];
#pragma unroll
    for (int n = 0; n < 2; ++n) {
        int bt = btb + n * 16 + lr;
        int t = bt & (T_LEN - 1);
        const unsigned short* hp = hprev + (size_t)bt * 32;
        hc[n] = *(const bf16x8*)(hp + 8 * lg);
        int bts = (t >= d) ? (bt - d) : bt;
        bf16x8 v = *(const bf16x8*)(hprev + (size_t)bts * 32 + 8 * lg);
        if (t < d) v = (bf16x8){0, 0, 0, 0, 0, 0, 0, 0};
        hs[n] = v;
#pragma unroll
        for (int m = 0; m < 2; ++m) hcc[n][m] = *(const uint2*)(hp + m * 16 + 4 * lg);
    }

    // conv MFMAs
    f32x4 zac[2][2];
#pragma unroll
    for (int m = 0; m < 2; ++m)
#pragma unroll
        for (int n = 0; n < 2; ++n) {
            f32x4 a = __builtin_amdgcn_mfma_f32_16x16x32_bf16(wd0[m], hs[n], (f32x4){0.f, 0.f, 0.f, 0.f}, 0, 0, 0);
            zac[m][n] = __builtin_amdgcn_mfma_f32_16x16x32_bf16(wd1[m], hc[n], a, 0, 0, 0);
        }

    // bias + tanh + pack -> per-wave LDS (C layout: col=bt, rows=oc m*16+4lg+r)
#pragma unroll
    for (int m = 0; m < 2; ++m) {
        float4 bdv = *(const float4*)(bd + m * 16 + 4 * lg);
#pragma unroll
        for (int n = 0; n < 2; ++n) {
            int rbt = n * 16 + lr;
            float z0 = ftanh(zac[m][n][0] + bdv.x);
            float z1 = ftanh(zac[m][n][1] + bdv.y);
            float z2 = ftanh(zac[m][n][2] + bdv.z);
            float z3 = ftanh(zac[m][n][3] + bdv.w);
            uint2 u;
            u.x = pack2(z0, z1);
            u.y = pack2(z2, z3);
            *(uint2*)(zp + rbt * 40 + m * 16 + 4 * lg) = u;   // ds_write_b64
        }
    }

    // res MFMAs: B-frag from LDS: col=bt, k=oc=8*lg+j
    f32x4 racc[2][2];
#pragma unroll
    for (int n = 0; n < 2; ++n) {
        int rbt = n * 16 + lr;
        bf16x8 zb = *(const bf16x8*)(zp + rbt * 40 + 8 * lg);  // ds_read_b128
#pragma unroll
        for (int m = 0; m < 2; ++m)
            racc[m][n] = __builtin_amdgcn_mfma_f32_16x16x32_bf16(wr[m], zb, (f32x4){0.f, 0.f, 0.f, 0.f}, 0, 0, 0);
    }

    // h' = hc + racc + br ; store bf16
#pragma unroll
    for (int m = 0; m < 2; ++m) {
        float4 brv = *(const float4*)(br + m * 16 + 4 * lg);
#pragma unroll
        for (int n = 0; n < 2; ++n) {
            int bt = btb + n * 16 + lr;
            float h0 = bflo(hcc[n][m].x) + racc[m][n][0] + brv.x;
            float h1 = bfhi(hcc[n][m].x) + racc[m][n][1] + brv.y;
            float h2 = bflo(hcc[n][m].y) + racc[m][n][2] + brv.z;
            float h3 = bfhi(hcc[n][m].y) + racc[m][n][3] + brv.w;
            uint2 u;
            u.x = pack2(h0, h1);
            u.y = pack2(h2, h3);
            *(uint2*)(hnext + (size_t)bt * 32 + m * 16 + 4 * lg) = u;
        }
    }
}

// ---------- skip GEMM (MFMA, prefetched): sk[bt][oc] = relu(Wsk@hist + bs_sum), bf16 ----------
__global__ __launch_bounds__(256) void k_skip(const unsigned short* __restrict__ hist,
                                              const unsigned short* __restrict__ Wsk,
                                              const float* __restrict__ bs_sum,
                                              unsigned short* __restrict__ sk) {
    int bt0 = blockIdx.x * 64;
    int lane = threadIdx.x & 63;
    int wq = threadIdx.x >> 6;
    int lr = lane & 15, lg = lane >> 4;
    int ocb = wq * 64;

    f32x4 acc[4][4];
#pragma unroll
    for (int m = 0; m < 4; ++m)
#pragma unroll
        for (int n = 0; n < 4; ++n) acc[m][n] = (f32x4){0.f, 0.f, 0.f, 0.f};

    const unsigned short* Abase = Wsk + (size_t)(ocb + lr) * KTOT + 8 * lg;
    const unsigned short* Bbase = hist + (size_t)(bt0 + lr) * 32 + 8 * lg;

    bf16x8 a[4], bb[4];
#pragma unroll
    for (int m = 0; m < 4; ++m) a[m] = *(const bf16x8*)(Abase + (size_t)m * 16 * KTOT);
#pragma unroll
    for (int n = 0; n < 4; ++n) bb[n] = *(const bf16x8*)(Bbase + (size_t)n * 16 * 32);

    for (int i = 0; i < NL; ++i) {
        int inext = (i + 1 < NL) ? (i + 1) : i;
        bf16x8 a2[4], bb2[4];
#pragma unroll
        for (int m = 0; m < 4; ++m) a2[m] = *(const bf16x8*)(Abase + (size_t)m * 16 * KTOT + inext * 32);
#pragma unroll
        for (int n = 0; n < 4; ++n) bb2[n] = *(const bf16x8*)(Bbase + (size_t)inext * NBT * 32 + (size_t)n * 16 * 32);
#pragma unroll
        for (int m = 0; m < 4; ++m)
#pragma unroll
            for (int n = 0; n < 4; ++n)
                acc[m][n] = __builtin_amdgcn_mfma_f32_16x16x32_bf16(a[m], bb[n], acc[m][n], 0, 0, 0);
#pragma unroll
        for (int m = 0; m < 4; ++m) a[m] = a2[m];
#pragma unroll
        for (int n = 0; n < 4; ++n) bb[n] = bb2[n];
    }

#pragma unroll
    for (int m = 0; m < 4; ++m) {
        int oc0 = ocb + m * 16 + lg * 4;
        float b0 = bs_sum[oc0], b1 = bs_sum[oc0 + 1], b2 = bs_sum[oc0 + 2], b3 = bs_sum[oc0 + 3];
#pragma unroll
        for (int n = 0; n < 4; ++n) {
            int bt = bt0 + n * 16 + lr;
            f32x4 v = acc[m][n];
            uint2 u;
            u.x = pack2(fmaxf(v[0] + b0, 0.f), fmaxf(v[1] + b1, 0.f));
            u.y = pack2(fmaxf(v[2] + b2, 0.f), fmaxf(v[3] + b3, 0.f));
            *(uint2*)&sk[(size_t)bt * SC + oc0] = u;
        }
    }
}

// ---------- final GEMM (MFMA): out[b][o][t] = Wfk[o][:] @ sk[bt][:] + bf[o], f32 out ----------
__global__ __launch_bounds__(256) void k_final(const unsigned short* __restrict__ sk,
                                               const unsigned short* __restrict__ Wfk,
                                               const float* __restrict__ bfv,
                                               float* __restrict__ outp) {
    int bt0 = blockIdx.x * 64;
    int lane = threadIdx.x & 63;
    int wq = threadIdx.x >> 6;
    int lr = lane & 15, lg = lane >> 4;
    int ob = wq * 64;

    f32x4 acc[4][4];
#pragma unroll
    for (int m = 0; m < 4; ++m)
#pragma unroll
        for (int n = 0; n < 4; ++n) acc[m][n] = (f32x4){0.f, 0.f, 0.f, 0.f};

#pragma unroll
    for (int kk = 0; kk < SC / 32; ++kk) {
        bf16x8 a[4], bb[4];
        const unsigned short* Arow = Wfk + (size_t)(ob + lr) * SC + kk * 32 + 8 * lg;
#pragma unroll
        for (int m = 0; m < 4; ++m) a[m] = *(const bf16x8*)(Arow + (size_t)m * 16 * SC);
        const unsigned short* Brow = sk + (size_t)(bt0 + lr) * SC + kk * 32 + 8 * lg;
#pragma unroll
        for (int n = 0; n < 4; ++n) bb[n] = *(const bf16x8*)(Brow + (size_t)n * 16 * SC);
#pragma unroll
        for (int m = 0; m < 4; ++m)
#pragma unroll
            for (int n = 0; n < 4; ++n)
                acc[m][n] = __builtin_amdgcn_mfma_f32_16x16x32_bf16(a[m], bb[n], acc[m][n], 0, 0, 0);
    }

    int b = bt0 >> 15;
    int t0 = bt0 & (T_LEN - 1);
#pragma unroll
    for (int m = 0; m < 4; ++m) {
        int o0 = ob + m * 16 + lg * 4;
#pragma unroll
        for (int n = 0; n < 4; ++n) {
            int t = t0 + n * 16 + lr;
            f32x4 v = acc[m][n];
#pragma unroll
            for (int r = 0; r < 4; ++r) {
                outp[((size_t)(b * OUTC + o0 + r) << 15) + t] = v[r] + bfv[o0 + r];
            }
        }
    }
}

extern "C" void kernel_launch(void* const* d_in, const int* in_sizes, int n_in,
                              void* d_out, int out_size, void* d_ws, size_t ws_size,
                              hipStream_t stream) {
    const float* x       = (const float*)d_in[0];
    const float* W_start = (const float*)d_in[1];
    const float* b_start = (const float*)d_in[2];
    const float* Wd      = (const float*)d_in[3];
    const float* bd      = (const float*)d_in[4];
    const float* Wr      = (const float*)d_in[5];
    const float* br      = (const float*)d_in[6];
    const float* Ws      = (const float*)d_in[7];
    const float* bs      = (const float*)d_in[8];
    const float* Wf      = (const float*)d_in[9];
    const float* bfv     = (const float*)d_in[10];

    char* wsb = (char*)d_ws;
    // weight packs (1 MB region)
    unsigned short* Wsk  = (unsigned short*)(wsb);                      // 655360 B
    unsigned short* Wfk  = (unsigned short*)(wsb + 655360);             // 131072 B
    unsigned short* Wd1k = (unsigned short*)(wsb + 786432);             // 81920 B
    unsigned short* Wd0k = (unsigned short*)(wsb + 868352);             // 81920 B
    unsigned short* Wrk  = (unsigned short*)(wsb + 950272);             // 81920 B
    float*          bs_sum = (float*)(wsb + 1032192);                   // 1024 B
    // stream slots 1..40 contiguous (skip GEMM reads this range), slot 0 in X region
    const size_t SLOTB = (size_t)NBT * 32 * 2;                          // 8,388,608 B
    char* S1 = wsb + (1 << 20);
    char* X  = S1 + 40 * SLOTB;                                         // slot0 / sk overlap
    unsigned short* sk = (unsigned short*)X;

    auto slotptr = [&](int i) -> unsigned short* {
        return (unsigned short*)(i == 0 ? X : S1 + (size_t)(i - 1) * SLOTB);
    };

    k_prep<<<(SC * KTOT + OUTC * SC + 3 * NL * 1024 + SC + 255) / 256, 256, 0, stream>>>(
        Ws, Wf, Wd, Wr, bs, Wsk, Wfk, Wd1k, Wd0k, Wrk, bs_sum);
    k_start<<<NBT / 256, 256, 0, stream>>>(x, W_start, b_start, slotptr(0));

    for (int i = 0; i < NL; ++i) {
        int d = 1 << (i % 10);
        k_layer<<<NBT / 128, 256, 0, stream>>>(slotptr(i), slotptr(i + 1),
                                               Wd1k + i * 1024, Wd0k + i * 1024, Wrk + i * 1024,
                                               bd + i * DC, br + i * RC, d);
    }

    k_skip<<<NBT / 64, 256, 0, stream>>>((unsigned short*)S1, Wsk, bs_sum, sk);
    k_final<<<NBT / 64, 256, 0, stream>>>(sk, Wfk, bfv, (float*)d_out);
}

// Round 4
// 555.270 us; speedup vs baseline: 6.7692x; 1.1772x over previous
//
#include <hip/hip_runtime.h>
#include <hip/hip_bf16.h>

#define T_LEN 32768
#define B_N   4
#define RC    32
#define DC    32
#define SC    256
#define OUTC  256
#define NL    40
#define KTOT  (NL * RC)   // 1280
#define NBT   (B_N * T_LEN)
#define D_ST  5
#define SLOTB ((size_t)NBT * 32 * 2)   // 8 MB per stream slot

typedef float f32x4 __attribute__((ext_vector_type(4)));
typedef short bf16x8 __attribute__((ext_vector_type(8)));
typedef __attribute__((address_space(3))) unsigned int lds_u32;
typedef __attribute__((address_space(1))) unsigned int glb_u32;

// ---------- helpers ----------
__device__ __forceinline__ unsigned short f2bf_bits(float f) {
    __hip_bfloat16 b = __float2bfloat16(f);
    unsigned short u;
    __builtin_memcpy(&u, &b, 2);
    return u;
}
__device__ __forceinline__ unsigned pack2(float a, float b) {
    return (unsigned)f2bf_bits(a) | ((unsigned)f2bf_bits(b) << 16);
}
__device__ __forceinline__ float bflo(unsigned u) { return __uint_as_float((u & 0xFFFFu) << 16); }
__device__ __forceinline__ float bfhi(unsigned u) { return __uint_as_float(u & 0xFFFF0000u); }
__device__ __forceinline__ float ftanh(float x) {
    float e = __expf(2.f * x);
    return 1.f - 2.f / (e + 1.f);
}
// exact counted vmcnt (compile-time n after unroll folds the switch)
__device__ __forceinline__ void wait_vmcnt(int n) {
    switch (n) {
        case 8:  asm volatile("s_waitcnt vmcnt(8)"  ::: "memory"); break;
        case 13: asm volatile("s_waitcnt vmcnt(13)" ::: "memory"); break;
        case 16: asm volatile("s_waitcnt vmcnt(16)" ::: "memory"); break;
        case 18: asm volatile("s_waitcnt vmcnt(18)" ::: "memory"); break;
        case 19: asm volatile("s_waitcnt vmcnt(19)" ::: "memory"); break;
        case 20: asm volatile("s_waitcnt vmcnt(20)" ::: "memory"); break;
        case 24: asm volatile("s_waitcnt vmcnt(24)" ::: "memory"); break;
        default: asm volatile("s_waitcnt vmcnt(28)" ::: "memory"); break;
    }
}

// ---------- prep: bf16 weight packs + bias sum ----------
__global__ __launch_bounds__(256) void k_prep(const float* __restrict__ Ws,
                                              const float* __restrict__ Wf,
                                              const float* __restrict__ Wd,
                                              const float* __restrict__ Wr,
                                              const float* __restrict__ bs,
                                              unsigned short* __restrict__ Wsk,
                                              unsigned short* __restrict__ Wfk,
                                              unsigned short* __restrict__ Wd1k,
                                              unsigned short* __restrict__ Wd0k,
                                              unsigned short* __restrict__ Wrk,
                                              float* __restrict__ bs_sum) {
    int g = blockIdx.x * 256 + threadIdx.x;
    if (g < SC * KTOT) {
        int oc = g / KTOT, k = g - oc * KTOT;
        int i = k >> 5, c = k & 31;
        Wsk[g] = f2bf_bits(Ws[(i * SC + oc) * RC + c]);
        return;
    }
    g -= SC * KTOT;
    if (g < OUTC * SC) { Wfk[g] = f2bf_bits(Wf[g]); return; }
    g -= OUTC * SC;
    if (g < NL * 1024) {
        int i = g >> 10, r = g & 1023;
        int o = r >> 5, c = r & 31;
        Wd1k[g] = f2bf_bits(Wd[((i * DC + o) * RC + c) * 2 + 1]);
        return;
    }
    g -= NL * 1024;
    if (g < NL * 1024) {
        int i = g >> 10, r = g & 1023;
        int o = r >> 5, c = r & 31;
        Wd0k[g] = f2bf_bits(Wd[((i * DC + o) * RC + c) * 2 + 0]);
        return;
    }
    g -= NL * 1024;
    if (g < NL * 1024) { Wrk[g] = f2bf_bits(Wr[g]); return; }
    g -= NL * 1024;
    if (g < SC) {
        float s = 0.f;
        for (int i = 0; i < NL; ++i) s += bs[i * SC + g];
        bs_sum[g] = s;
    }
}

// ---------- start conv -> bf16 stream slot 0 ----------
__global__ __launch_bounds__(256) void k_start(const float* __restrict__ x,
                                               const float* __restrict__ Wst,
                                               const float* __restrict__ bst,
                                               unsigned short* __restrict__ h0) {
    int g = blockIdx.x * 256 + threadIdx.x;   // bt
    float xv = x[g];
    unsigned u[16];
#pragma unroll
    for (int q = 0; q < 16; ++q) {
        float a = Wst[2 * q] * xv + bst[2 * q];
        float b = Wst[2 * q + 1] * xv + bst[2 * q + 1];
        u[q] = pack2(a, b);
    }
    unsigned short* op = h0 + (size_t)g * 32;
#pragma unroll
    for (int q = 0; q < 4; ++q) *(uint4*)&op[q * 8] = *(uint4*)&u[q * 4];
}

// ---------- one WaveNet layer: MFMA, bf16 stream (unchanged from R2) ----------
__global__ __launch_bounds__(256, 4) void k_layer(const unsigned short* __restrict__ hprev,
                                                  unsigned short* __restrict__ hnext,
                                                  const unsigned short* __restrict__ Wd1k,
                                                  const unsigned short* __restrict__ Wd0k,
                                                  const unsigned short* __restrict__ Wrk,
                                                  const float* __restrict__ bd,
                                                  const float* __restrict__ br,
                                                  int d) {
    __shared__ unsigned short zbuf[4][32 * 40];
    int lane = threadIdx.x & 63;
    int wq = threadIdx.x >> 6;
    int lr = lane & 15, lg = lane >> 4;
    int btb = blockIdx.x * 128 + wq * 32;
    unsigned short* zp = &zbuf[wq][0];

    bf16x8 wd1[2], wd0[2], wr[2];
#pragma unroll
    for (int m = 0; m < 2; ++m) {
        int ao = (m * 16 + lr) * 32 + 8 * lg;
        wd1[m] = *(const bf16x8*)(Wd1k + ao);
        wd0[m] = *(const bf16x8*)(Wd0k + ao);
        wr[m]  = *(const bf16x8*)(Wrk + ao);
    }

    bf16x8 hc[2], hs[2];
    uint2 hcc[2][2];
#pragma unroll
    for (int n = 0; n < 2; ++n) {
        int bt = btb + n * 16 + lr;
        int t = bt & (T_LEN - 1);
        const unsigned short* hp = hprev + (size_t)bt * 32;
        hc[n] = *(const bf16x8*)(hp + 8 * lg);
        int bts = (t >= d) ? (bt - d) : bt;
        bf16x8 v = *(const bf16x8*)(hprev + (size_t)bts * 32 + 8 * lg);
        if (t < d) v = (bf16x8){0, 0, 0, 0, 0, 0, 0, 0};
        hs[n] = v;
#pragma unroll
        for (int m = 0; m < 2; ++m) hcc[n][m] = *(const uint2*)(hp + m * 16 + 4 * lg);
    }

    f32x4 zac[2][2];
#pragma unroll
    for (int m = 0; m < 2; ++m)
#pragma unroll
        for (int n = 0; n < 2; ++n) {
            f32x4 a = __builtin_amdgcn_mfma_f32_16x16x32_bf16(wd0[m], hs[n], (f32x4){0.f, 0.f, 0.f, 0.f}, 0, 0, 0);
            zac[m][n] = __builtin_amdgcn_mfma_f32_16x16x32_bf16(wd1[m], hc[n], a, 0, 0, 0);
        }

#pragma unroll
    for (int m = 0; m < 2; ++m) {
        float4 bdv = *(const float4*)(bd + m * 16 + 4 * lg);
#pragma unroll
        for (int n = 0; n < 2; ++n) {
            int rbt = n * 16 + lr;
            float z0 = ftanh(zac[m][n][0] + bdv.x);
            float z1 = ftanh(zac[m][n][1] + bdv.y);
            float z2 = ftanh(zac[m][n][2] + bdv.z);
            float z3 = ftanh(zac[m][n][3] + bdv.w);
            uint2 u;
            u.x = pack2(z0, z1);
            u.y = pack2(z2, z3);
            *(uint2*)(zp + rbt * 40 + m * 16 + 4 * lg) = u;
        }
    }

    f32x4 racc[2][2];
#pragma unroll
    for (int n = 0; n < 2; ++n) {
        int rbt = n * 16 + lr;
        bf16x8 zb = *(const bf16x8*)(zp + rbt * 40 + 8 * lg);
#pragma unroll
        for (int m = 0; m < 2; ++m)
            racc[m][n] = __builtin_amdgcn_mfma_f32_16x16x32_bf16(wr[m], zb, (f32x4){0.f, 0.f, 0.f, 0.f}, 0, 0, 0);
    }

#pragma unroll
    for (int m = 0; m < 2; ++m) {
        float4 brv = *(const float4*)(br + m * 16 + 4 * lg);
#pragma unroll
        for (int n = 0; n < 2; ++n) {
            int bt = btb + n * 16 + lr;
            float h0 = bflo(hcc[n][m].x) + racc[m][n][0] + brv.x;
            float h1 = bfhi(hcc[n][m].x) + racc[m][n][1] + brv.y;
            float h2 = bflo(hcc[n][m].y) + racc[m][n][2] + brv.z;
            float h3 = bfhi(hcc[n][m].y) + racc[m][n][3] + brv.w;
            uint2 u;
            u.x = pack2(h0, h1);
            u.y = pack2(h2, h3);
            *(uint2*)(hnext + (size_t)bt * 32 + m * 16 + 4 * lg) = u;
        }
    }
}

// ---------- fused skip + final GEMM ----------
// Phase 1: acc = Wsk @ hist (K=1280) with depth-5 global_load_lds pipeline, counted vmcnt.
// sk tile (64bt x 256oc bf16) -> LDS (swizzled). Phase 2: out = Wfk @ sk + bf.
__global__ __launch_bounds__(256, 3) void k_skipfinal(const unsigned short* __restrict__ hist,
                                                      const unsigned short* __restrict__ Wsk,
                                                      const unsigned short* __restrict__ Wfk,
                                                      const float* __restrict__ bs_sum,
                                                      const float* __restrict__ bfv,
                                                      float* __restrict__ outp) {
    __shared__ char smem[D_ST * 4096 + 64 * 512];   // 52 KB: 5 stage bufs + sk tile
    const int tid = threadIdx.x;
    const int lane = tid & 63, wq = tid >> 6;
    const int lr = lane & 15, lg = lane >> 4;
    const int bt0 = blockIdx.x * 64;
    const int ocb = wq * 64;
    const char* histb = (const char*)hist;

    // staging: linear LDS dst (lane*16), pre-swizzled global src (involution on bits 4-6 from bits 7-9)
    const int stloc = tid * 16;
    const int stsw = stloc ^ (((stloc >> 7) & 7) << 4);

    // A (Wsk) per-m base pointers
    const unsigned short* Ab0 = Wsk + (size_t)(ocb + lr) * KTOT + 8 * lg;
    const unsigned short* Ab1 = Ab0 + (size_t)16 * KTOT;
    const unsigned short* Ab2 = Ab0 + (size_t)32 * KTOT;
    const unsigned short* Ab3 = Ab0 + (size_t)48 * KTOT;

    // B ds_read swizzled offsets per n
    int rbq[4];
#pragma unroll
    for (int n = 0; n < 4; ++n) {
        int L = (n * 16 + lr) * 64 + lg * 16;
        rbq[n] = L ^ (((L >> 7) & 7) << 4);
    }

    f32x4 acc[4][4];
#pragma unroll
    for (int m = 0; m < 4; ++m)
#pragma unroll
        for (int n = 0; n < 4; ++n) acc[m][n] = (f32x4){0.f, 0.f, 0.f, 0.f};

    bf16x8 a[3][4];

    // ---- prologue: S0..S3 then A0,A1 (order pinned by fences; vmcnt table assumes it) ----
#pragma unroll
    for (int s = 0; s < 4; ++s) {
        const char* src = histb + (size_t)s * SLOTB + (size_t)bt0 * 64 + stsw;
        char* dst = smem + s * 4096 + wq * 1024;
        __builtin_amdgcn_global_load_lds((const glb_u32*)src, (lds_u32*)dst, 16, 0, 0);
    }
    asm volatile("" ::: "memory");
    a[0][0] = *(const bf16x8*)(Ab0); a[0][1] = *(const bf16x8*)(Ab1);
    a[0][2] = *(const bf16x8*)(Ab2); a[0][3] = *(const bf16x8*)(Ab3);
    a[1][0] = *(const bf16x8*)(Ab0 + 32); a[1][1] = *(const bf16x8*)(Ab1 + 32);
    a[1][2] = *(const bf16x8*)(Ab2 + 32); a[1][3] = *(const bf16x8*)(Ab3 + 32);
    asm volatile("" ::: "memory");

    // ---- main loop (fully unrolled; per-iter VMEM order: A x4 then STAGE x1) ----
#pragma unroll
    for (int i = 0; i < NL; ++i) {
        if (i + 2 < NL) {
            a[(i + 2) % 3][0] = *(const bf16x8*)(Ab0 + (i + 2) * 32);
            a[(i + 2) % 3][1] = *(const bf16x8*)(Ab1 + (i + 2) * 32);
            a[(i + 2) % 3][2] = *(const bf16x8*)(Ab2 + (i + 2) * 32);
            a[(i + 2) % 3][3] = *(const bf16x8*)(Ab3 + (i + 2) * 32);
        }
        if (i + 4 < NL) {
            const char* src = histb + (size_t)(i + 4) * SLOTB + (size_t)bt0 * 64 + stsw;
            char* dst = smem + ((i + 4) % D_ST) * 4096 + wq * 1024;
            __builtin_amdgcn_global_load_lds((const glb_u32*)src, (lds_u32*)dst, 16, 0, 0);
        }
        // exact count of VMEM ops newer than S(i) (minimal ordering -> safe)
        int Ni = (i == 0) ? 16 : (i == 1) ? 20 : (i == 2) ? 24 : (i == 3) ? 28
               : (i <= 35) ? 20 : (i == 36) ? 19 : (i == 37) ? 18 : (i == 38) ? 13 : 8;
        wait_vmcnt(Ni);
        __builtin_amdgcn_s_barrier();

        const char* sb = smem + (i % D_ST) * 4096;
        bf16x8 b0 = *(const bf16x8*)(sb + rbq[0]);
        bf16x8 b1 = *(const bf16x8*)(sb + rbq[1]);
        bf16x8 b2 = *(const bf16x8*)(sb + rbq[2]);
        bf16x8 b3 = *(const bf16x8*)(sb + rbq[3]);
#pragma unroll
        for (int m = 0; m < 4; ++m) {
            acc[m][0] = __builtin_amdgcn_mfma_f32_16x16x32_bf16(a[i % 3][m], b0, acc[m][0], 0, 0, 0);
            acc[m][1] = __builtin_amdgcn_mfma_f32_16x16x32_bf16(a[i % 3][m], b1, acc[m][1], 0, 0, 0);
            acc[m][2] = __builtin_amdgcn_mfma_f32_16x16x32_bf16(a[i % 3][m], b2, acc[m][2], 0, 0, 0);
            acc[m][3] = __builtin_amdgcn_mfma_f32_16x16x32_bf16(a[i % 3][m], b3, acc[m][3], 0, 0, 0);
        }
        __builtin_amdgcn_s_barrier();
    }

    // ---- sk epilogue: bias + relu + bf16 -> LDS (swizzled, row stride 512B) ----
    char* skb = smem + D_ST * 4096;
#pragma unroll
    for (int m = 0; m < 4; ++m) {
        int oc0 = ocb + m * 16 + lg * 4;
        float c0 = bs_sum[oc0], c1 = bs_sum[oc0 + 1], c2 = bs_sum[oc0 + 2], c3 = bs_sum[oc0 + 3];
#pragma unroll
        for (int n = 0; n < 4; ++n) {
            int bt = n * 16 + lr;
            f32x4 v = acc[m][n];
            uint2 u;
            u.x = pack2(fmaxf(v[0] + c0, 0.f), fmaxf(v[1] + c1, 0.f));
            u.y = pack2(fmaxf(v[2] + c2, 0.f), fmaxf(v[3] + c3, 0.f));
            int L = bt * 512 + oc0 * 2;
            *(uint2*)(skb + (L ^ ((bt & 7) << 4))) = u;
        }
    }
    __syncthreads();

    // ---- phase 2: final GEMM out = Wfk @ sk + bf ----
    f32x4 acc2[4][4];
#pragma unroll
    for (int m = 0; m < 4; ++m)
#pragma unroll
        for (int n = 0; n < 4; ++n) acc2[m][n] = (f32x4){0.f, 0.f, 0.f, 0.f};

    const unsigned short* Fb0 = Wfk + (size_t)(ocb + lr) * SC + 8 * lg;
    const unsigned short* Fb1 = Fb0 + (size_t)16 * SC;
    const unsigned short* Fb2 = Fb0 + (size_t)32 * SC;
    const unsigned short* Fb3 = Fb0 + (size_t)48 * SC;

#pragma unroll
    for (int kk = 0; kk < SC / 32; ++kk) {
        bf16x8 fa[4];
        fa[0] = *(const bf16x8*)(Fb0 + kk * 32);
        fa[1] = *(const bf16x8*)(Fb1 + kk * 32);
        fa[2] = *(const bf16x8*)(Fb2 + kk * 32);
        fa[3] = *(const bf16x8*)(Fb3 + kk * 32);
        bf16x8 sbv[4];
#pragma unroll
        for (int n = 0; n < 4; ++n) {
            int bt = n * 16 + lr;
            int L = bt * 512 + kk * 64 + lg * 16;
            sbv[n] = *(const bf16x8*)(skb + (L ^ ((bt & 7) << 4)));
        }
#pragma unroll
        for (int m = 0; m < 4; ++m)
#pragma unroll
            for (int n = 0; n < 4; ++n)
                acc2[m][n] = __builtin_amdgcn_mfma_f32_16x16x32_bf16(fa[m], sbv[n], acc2[m][n], 0, 0, 0);
    }

    int b = bt0 >> 15;
    int t0 = bt0 & (T_LEN - 1);
#pragma unroll
    for (int m = 0; m < 4; ++m) {
        int o0 = ocb + m * 16 + lg * 4;
        float q0 = bfv[o0], q1 = bfv[o0 + 1], q2 = bfv[o0 + 2], q3 = bfv[o0 + 3];
#pragma unroll
        for (int n = 0; n < 4; ++n) {
            int t = t0 + n * 16 + lr;
            f32x4 v = acc2[m][n];
            outp[((size_t)(b * OUTC + o0 + 0) << 15) + t] = v[0] + q0;
            outp[((size_t)(b * OUTC + o0 + 1) << 15) + t] = v[1] + q1;
            outp[((size_t)(b * OUTC + o0 + 2) << 15) + t] = v[2] + q2;
            outp[((size_t)(b * OUTC + o0 + 3) << 15) + t] = v[3] + q3;
        }
    }
}

extern "C" void kernel_launch(void* const* d_in, const int* in_sizes, int n_in,
                              void* d_out, int out_size, void* d_ws, size_t ws_size,
                              hipStream_t stream) {
    const float* x       = (const float*)d_in[0];
    const float* W_start = (const float*)d_in[1];
    const float* b_start = (const float*)d_in[2];
    const float* Wd      = (const float*)d_in[3];
    const float* bd      = (const float*)d_in[4];
    const float* Wr      = (const float*)d_in[5];
    const float* br      = (const float*)d_in[6];
    const float* Ws      = (const float*)d_in[7];
    const float* bs      = (const float*)d_in[8];
    const float* Wf      = (const float*)d_in[9];
    const float* bfv     = (const float*)d_in[10];

    char* wsb = (char*)d_ws;
    unsigned short* Wsk  = (unsigned short*)(wsb);                      // 655360 B
    unsigned short* Wfk  = (unsigned short*)(wsb + 655360);             // 131072 B
    unsigned short* Wd1k = (unsigned short*)(wsb + 786432);             // 81920 B
    unsigned short* Wd0k = (unsigned short*)(wsb + 868352);             // 81920 B
    unsigned short* Wrk  = (unsigned short*)(wsb + 950272);             // 81920 B
    float*          bs_sum = (float*)(wsb + 1032192);                   // 1024 B
    char* S1 = wsb + (1 << 20);            // stream slots 1..40 (= hist layers 0..39)
    char* X  = S1 + 40 * SLOTB;            // slot 0

    auto slotptr = [&](int i) -> unsigned short* {
        return (unsigned short*)(i == 0 ? X : S1 + (size_t)(i - 1) * SLOTB);
    };

    k_prep<<<(SC * KTOT + OUTC * SC + 3 * NL * 1024 + SC + 255) / 256, 256, 0, stream>>>(
        Ws, Wf, Wd, Wr, bs, Wsk, Wfk, Wd1k, Wd0k, Wrk, bs_sum);
    k_start<<<NBT / 256, 256, 0, stream>>>(x, W_start, b_start, slotptr(0));

    for (int i = 0; i < NL; ++i) {
        int d = 1 << (i % 10);
        k_layer<<<NBT / 128, 256, 0, stream>>>(slotptr(i), slotptr(i + 1),
                                               Wd1k + i * 1024, Wd0k + i * 1024, Wrk + i * 1024,
                                               bd + i * DC, br + i * RC, d);
    }

    k_skipfinal<<<NBT / 64, 256, 0, stream>>>((unsigned short*)S1, Wsk, Wfk, bs_sum, bfv, (float*)d_out);
}

// Round 5
// 554.643 us; speedup vs baseline: 6.7769x; 1.0011x over previous
//
#include <hip/hip_runtime.h>
#include <hip/hip_bf16.h>

#define T_LEN 32768
#define B_N   4
#define RC    32
#define DC    32
#define SC    256
#define OUTC  256
#define NL    40
#define KTOT  (NL * RC)   // 1280
#define NBT   (B_N * T_LEN)
#define D_ST  5
#define SLOTB ((size_t)NBT * 32 * 2)   // 8 MB per stream slot

typedef float f32x4 __attribute__((ext_vector_type(4)));
typedef short bf16x8 __attribute__((ext_vector_type(8)));
typedef __attribute__((address_space(3))) unsigned int lds_u32;
typedef __attribute__((address_space(3))) char lds_char;
typedef __attribute__((address_space(1))) unsigned int glb_u32;

// ---------- helpers ----------
__device__ __forceinline__ unsigned short f2bf_bits(float f) {
    __hip_bfloat16 b = __float2bfloat16(f);
    unsigned short u;
    __builtin_memcpy(&u, &b, 2);
    return u;
}
__device__ __forceinline__ unsigned pack2(float a, float b) {
    return (unsigned)f2bf_bits(a) | ((unsigned)f2bf_bits(b) << 16);
}
__device__ __forceinline__ float bflo(unsigned u) { return __uint_as_float((u & 0xFFFFu) << 16); }
__device__ __forceinline__ float bfhi(unsigned u) { return __uint_as_float(u & 0xFFFF0000u); }
__device__ __forceinline__ float ftanh(float x) {
    float e = __expf(2.f * x);
    return 1.f - 2.f / (e + 1.f);
}
// exact counted vmcnt (compile-time n after unroll folds the switch)
__device__ __forceinline__ void wait_vmcnt(int n) {
    switch (n) {
        case 8:  asm volatile("s_waitcnt vmcnt(8)"  ::: "memory"); break;
        case 13: asm volatile("s_waitcnt vmcnt(13)" ::: "memory"); break;
        case 16: asm volatile("s_waitcnt vmcnt(16)" ::: "memory"); break;
        case 18: asm volatile("s_waitcnt vmcnt(18)" ::: "memory"); break;
        case 19: asm volatile("s_waitcnt vmcnt(19)" ::: "memory"); break;
        case 20: asm volatile("s_waitcnt vmcnt(20)" ::: "memory"); break;
        case 24: asm volatile("s_waitcnt vmcnt(24)" ::: "memory"); break;
        default: asm volatile("s_waitcnt vmcnt(28)" ::: "memory"); break;
    }
}

// ---------- prep: bf16 weight packs + bias sum ----------
__global__ __launch_bounds__(256) void k_prep(const float* __restrict__ Ws,
                                              const float* __restrict__ Wf,
                                              const float* __restrict__ Wd,
                                              const float* __restrict__ Wr,
                                              const float* __restrict__ bs,
                                              unsigned short* __restrict__ Wsk,
                                              unsigned short* __restrict__ Wfk,
                                              unsigned short* __restrict__ Wd1k,
                                              unsigned short* __restrict__ Wd0k,
                                              unsigned short* __restrict__ Wrk,
                                              float* __restrict__ bs_sum) {
    int g = blockIdx.x * 256 + threadIdx.x;
    if (g < SC * KTOT) {
        int oc = g / KTOT, k = g - oc * KTOT;
        int i = k >> 5, c = k & 31;
        Wsk[g] = f2bf_bits(Ws[(i * SC + oc) * RC + c]);
        return;
    }
    g -= SC * KTOT;
    if (g < OUTC * SC) { Wfk[g] = f2bf_bits(Wf[g]); return; }
    g -= OUTC * SC;
    if (g < NL * 1024) {
        int i = g >> 10, r = g & 1023;
        int o = r >> 5, c = r & 31;
        Wd1k[g] = f2bf_bits(Wd[((i * DC + o) * RC + c) * 2 + 1]);
        return;
    }
    g -= NL * 1024;
    if (g < NL * 1024) {
        int i = g >> 10, r = g & 1023;
        int o = r >> 5, c = r & 31;
        Wd0k[g] = f2bf_bits(Wd[((i * DC + o) * RC + c) * 2 + 0]);
        return;
    }
    g -= NL * 1024;
    if (g < NL * 1024) { Wrk[g] = f2bf_bits(Wr[g]); return; }
    g -= NL * 1024;
    if (g < SC) {
        float s = 0.f;
        for (int i = 0; i < NL; ++i) s += bs[i * SC + g];
        bs_sum[g] = s;
    }
}

// ---------- start conv -> bf16 stream slot 0 ----------
__global__ __launch_bounds__(256) void k_start(const float* __restrict__ x,
                                               const float* __restrict__ Wst,
                                               const float* __restrict__ bst,
                                               unsigned short* __restrict__ h0) {
    int g = blockIdx.x * 256 + threadIdx.x;   // bt
    float xv = x[g];
    unsigned u[16];
#pragma unroll
    for (int q = 0; q < 16; ++q) {
        float a = Wst[2 * q] * xv + bst[2 * q];
        float b = Wst[2 * q + 1] * xv + bst[2 * q + 1];
        u[q] = pack2(a, b);
    }
    unsigned short* op = h0 + (size_t)g * 32;
#pragma unroll
    for (int q = 0; q < 4; ++q) *(uint4*)&op[q * 8] = *(uint4*)&u[q * 4];
}

// ---------- one WaveNet layer: MFMA, bf16 stream (unchanged) ----------
__global__ __launch_bounds__(256, 4) void k_layer(const unsigned short* __restrict__ hprev,
                                                  unsigned short* __restrict__ hnext,
                                                  const unsigned short* __restrict__ Wd1k,
                                                  const unsigned short* __restrict__ Wd0k,
                                                  const unsigned short* __restrict__ Wrk,
                                                  const float* __restrict__ bd,
                                                  const float* __restrict__ br,
                                                  int d) {
    __shared__ unsigned short zbuf[4][32 * 40];
    int lane = threadIdx.x & 63;
    int wq = threadIdx.x >> 6;
    int lr = lane & 15, lg = lane >> 4;
    int btb = blockIdx.x * 128 + wq * 32;
    unsigned short* zp = &zbuf[wq][0];

    bf16x8 wd1[2], wd0[2], wr[2];
#pragma unroll
    for (int m = 0; m < 2; ++m) {
        int ao = (m * 16 + lr) * 32 + 8 * lg;
        wd1[m] = *(const bf16x8*)(Wd1k + ao);
        wd0[m] = *(const bf16x8*)(Wd0k + ao);
        wr[m]  = *(const bf16x8*)(Wrk + ao);
    }

    bf16x8 hc[2], hs[2];
    uint2 hcc[2][2];
#pragma unroll
    for (int n = 0; n < 2; ++n) {
        int bt = btb + n * 16 + lr;
        int t = bt & (T_LEN - 1);
        const unsigned short* hp = hprev + (size_t)bt * 32;
        hc[n] = *(const bf16x8*)(hp + 8 * lg);
        int bts = (t >= d) ? (bt - d) : bt;
        bf16x8 v = *(const bf16x8*)(hprev + (size_t)bts * 32 + 8 * lg);
        if (t < d) v = (bf16x8){0, 0, 0, 0, 0, 0, 0, 0};
        hs[n] = v;
#pragma unroll
        for (int m = 0; m < 2; ++m) hcc[n][m] = *(const uint2*)(hp + m * 16 + 4 * lg);
    }

    f32x4 zac[2][2];
#pragma unroll
    for (int m = 0; m < 2; ++m)
#pragma unroll
        for (int n = 0; n < 2; ++n) {
            f32x4 a = __builtin_amdgcn_mfma_f32_16x16x32_bf16(wd0[m], hs[n], (f32x4){0.f, 0.f, 0.f, 0.f}, 0, 0, 0);
            zac[m][n] = __builtin_amdgcn_mfma_f32_16x16x32_bf16(wd1[m], hc[n], a, 0, 0, 0);
        }

#pragma unroll
    for (int m = 0; m < 2; ++m) {
        float4 bdv = *(const float4*)(bd + m * 16 + 4 * lg);
#pragma unroll
        for (int n = 0; n < 2; ++n) {
            int rbt = n * 16 + lr;
            float z0 = ftanh(zac[m][n][0] + bdv.x);
            float z1 = ftanh(zac[m][n][1] + bdv.y);
            float z2 = ftanh(zac[m][n][2] + bdv.z);
            float z3 = ftanh(zac[m][n][3] + bdv.w);
            uint2 u;
            u.x = pack2(z0, z1);
            u.y = pack2(z2, z3);
            *(uint2*)(zp + rbt * 40 + m * 16 + 4 * lg) = u;
        }
    }

    f32x4 racc[2][2];
#pragma unroll
    for (int n = 0; n < 2; ++n) {
        int rbt = n * 16 + lr;
        bf16x8 zb = *(const bf16x8*)(zp + rbt * 40 + 8 * lg);
#pragma unroll
        for (int m = 0; m < 2; ++m)
            racc[m][n] = __builtin_amdgcn_mfma_f32_16x16x32_bf16(wr[m], zb, (f32x4){0.f, 0.f, 0.f, 0.f}, 0, 0, 0);
    }

#pragma unroll
    for (int m = 0; m < 2; ++m) {
        float4 brv = *(const float4*)(br + m * 16 + 4 * lg);
#pragma unroll
        for (int n = 0; n < 2; ++n) {
            int bt = btb + n * 16 + lr;
            float h0 = bflo(hcc[n][m].x) + racc[m][n][0] + brv.x;
            float h1 = bfhi(hcc[n][m].x) + racc[m][n][1] + brv.y;
            float h2 = bflo(hcc[n][m].y) + racc[m][n][2] + brv.z;
            float h3 = bfhi(hcc[n][m].y) + racc[m][n][3] + brv.w;
            uint2 u;
            u.x = pack2(h0, h1);
            u.y = pack2(h2, h3);
            *(uint2*)(hnext + (size_t)bt * 32 + m * 16 + 4 * lg) = u;
        }
    }
}

// ---------- fused skip + final GEMM ----------
// Phase 1: acc = Wsk @ hist (K=1280), depth-5 global_load_lds pipeline, counted vmcnt,
// B-fragments read via inline-asm ds_read_b128 (keeps compiler from inserting vmcnt(0)
// alias-drains against the global_load_lds writes). Phase 2: out = Wfk @ sk + bf.
__global__ __launch_bounds__(256, 3) void k_skipfinal(const unsigned short* __restrict__ hist,
                                                      const unsigned short* __restrict__ Wsk,
                                                      const unsigned short* __restrict__ Wfk,
                                                      const float* __restrict__ bs_sum,
                                                      const float* __restrict__ bfv,
                                                      float* __restrict__ outp) {
    __shared__ char smem[D_ST * 4096 + 64 * 512];   // 52 KB: 5 stage bufs + sk tile
    const int tid = threadIdx.x;
    const int lane = tid & 63, wq = tid >> 6;
    const int lr = lane & 15, lg = lane >> 4;
    const int bt0 = blockIdx.x * 64;
    const int ocb = wq * 64;
    const char* histb = (const char*)hist;
    lds_char* smem3 = (lds_char*)smem;

    // staging: linear LDS dst (lane*16), pre-swizzled global src (bits 4-6 ^= bits 7-9)
    const int stloc = tid * 16;
    const int stsw = stloc ^ (((stloc >> 7) & 7) << 4);

    // A (Wsk) per-m base pointers
    const unsigned short* Ab0 = Wsk + (size_t)(ocb + lr) * KTOT + 8 * lg;
    const unsigned short* Ab1 = Ab0 + (size_t)16 * KTOT;
    const unsigned short* Ab2 = Ab0 + (size_t)32 * KTOT;
    const unsigned short* Ab3 = Ab0 + (size_t)48 * KTOT;

    // B ds_read swizzled offsets per n
    int rbq[4];
#pragma unroll
    for (int n = 0; n < 4; ++n) {
        int L = (n * 16 + lr) * 64 + lg * 16;
        rbq[n] = L ^ (((L >> 7) & 7) << 4);
    }

    f32x4 acc[4][4];
#pragma unroll
    for (int m = 0; m < 4; ++m)
#pragma unroll
        for (int n = 0; n < 4; ++n) acc[m][n] = (f32x4){0.f, 0.f, 0.f, 0.f};

    bf16x8 a[3][4];

    // ---- prologue: S0..S3 then A0,A1 (order pinned; vmcnt table assumes it) ----
#pragma unroll
    for (int s = 0; s < 4; ++s) {
        const char* src = histb + (size_t)s * SLOTB + (size_t)bt0 * 64 + stsw;
        char* dst = smem + s * 4096 + wq * 1024;
        __builtin_amdgcn_global_load_lds((const glb_u32*)src, (lds_u32*)dst, 16, 0, 0);
    }
    asm volatile("" ::: "memory");
    a[0][0] = *(const bf16x8*)(Ab0); a[0][1] = *(const bf16x8*)(Ab1);
    a[0][2] = *(const bf16x8*)(Ab2); a[0][3] = *(const bf16x8*)(Ab3);
    a[1][0] = *(const bf16x8*)(Ab0 + 32); a[1][1] = *(const bf16x8*)(Ab1 + 32);
    a[1][2] = *(const bf16x8*)(Ab2 + 32); a[1][3] = *(const bf16x8*)(Ab3 + 32);
    asm volatile("" ::: "memory");

    // ---- main loop (fully unrolled; per-iter VMEM order: A x4 then STAGE x1) ----
#pragma unroll
    for (int i = 0; i < NL; ++i) {
        if (i + 2 < NL) {
            a[(i + 2) % 3][0] = *(const bf16x8*)(Ab0 + (i + 2) * 32);
            a[(i + 2) % 3][1] = *(const bf16x8*)(Ab1 + (i + 2) * 32);
            a[(i + 2) % 3][2] = *(const bf16x8*)(Ab2 + (i + 2) * 32);
            a[(i + 2) % 3][3] = *(const bf16x8*)(Ab3 + (i + 2) * 32);
        }
        if (i + 4 < NL) {
            const char* src = histb + (size_t)(i + 4) * SLOTB + (size_t)bt0 * 64 + stsw;
            char* dst = smem + ((i + 4) % D_ST) * 4096 + wq * 1024;
            __builtin_amdgcn_global_load_lds((const glb_u32*)src, (lds_u32*)dst, 16, 0, 0);
        }
        // exact count of VMEM ops newer than S(i); safe for any within-iter order
        int Ni = (i == 0) ? 16 : (i == 1) ? 20 : (i == 2) ? 24 : (i == 3) ? 28
               : (i <= 35) ? 20 : (i == 36) ? 19 : (i == 37) ? 18 : (i == 38) ? 13 : 8;
        wait_vmcnt(Ni);
        __builtin_amdgcn_s_barrier();

        lds_char* sb3 = smem3 + (i % D_ST) * 4096;
        bf16x8 b0, b1, b2, b3;
        asm volatile("ds_read_b128 %0, %1" : "=v"(b0) : "v"(sb3 + rbq[0]));
        asm volatile("ds_read_b128 %0, %1" : "=v"(b1) : "v"(sb3 + rbq[1]));
        asm volatile("ds_read_b128 %0, %1" : "=v"(b2) : "v"(sb3 + rbq[2]));
        asm volatile("ds_read_b128 %0, %1" : "=v"(b3) : "v"(sb3 + rbq[3]));
        asm volatile("s_waitcnt lgkmcnt(0)" ::: "memory");
        __builtin_amdgcn_sched_barrier(0);
#pragma unroll
        for (int m = 0; m < 4; ++m) {
            acc[m][0] = __builtin_amdgcn_mfma_f32_16x16x32_bf16(a[i % 3][m], b0, acc[m][0], 0, 0, 0);
            acc[m][1] = __builtin_amdgcn_mfma_f32_16x16x32_bf16(a[i % 3][m], b1, acc[m][1], 0, 0, 0);
            acc[m][2] = __builtin_amdgcn_mfma_f32_16x16x32_bf16(a[i % 3][m], b2, acc[m][2], 0, 0, 0);
            acc[m][3] = __builtin_amdgcn_mfma_f32_16x16x32_bf16(a[i % 3][m], b3, acc[m][3], 0, 0, 0);
        }
        __builtin_amdgcn_s_barrier();
    }

    // ---- sk epilogue: bias + relu + bf16 -> LDS (swizzled, row stride 512B) ----
    char* skb = smem + D_ST * 4096;
#pragma unroll
    for (int m = 0; m < 4; ++m) {
        int oc0 = ocb + m * 16 + lg * 4;
        float c0 = bs_sum[oc0], c1 = bs_sum[oc0 + 1], c2 = bs_sum[oc0 + 2], c3 = bs_sum[oc0 + 3];
#pragma unroll
        for (int n = 0; n < 4; ++n) {
            int bt = n * 16 + lr;
            f32x4 v = acc[m][n];
            uint2 u;
            u.x = pack2(fmaxf(v[0] + c0, 0.f), fmaxf(v[1] + c1, 0.f));
            u.y = pack2(fmaxf(v[2] + c2, 0.f), fmaxf(v[3] + c3, 0.f));
            int L = bt * 512 + oc0 * 2;
            *(uint2*)(skb + (L ^ ((bt & 7) << 4))) = u;
        }
    }
    __syncthreads();

    // ---- phase 2: final GEMM out = Wfk @ sk + bf ----
    f32x4 acc2[4][4];
#pragma unroll
    for (int m = 0; m < 4; ++m)
#pragma unroll
        for (int n = 0; n < 4; ++n) acc2[m][n] = (f32x4){0.f, 0.f, 0.f, 0.f};

    const unsigned short* Fb0 = Wfk + (size_t)(ocb + lr) * SC + 8 * lg;
    const unsigned short* Fb1 = Fb0 + (size_t)16 * SC;
    const unsigned short* Fb2 = Fb0 + (size_t)32 * SC;
    const unsigned short* Fb3 = Fb0 + (size_t)48 * SC;

#pragma unroll
    for (int kk = 0; kk < SC / 32; ++kk) {
        bf16x8 fa[4];
        fa[0] = *(const bf16x8*)(Fb0 + kk * 32);
        fa[1] = *(const bf16x8*)(Fb1 + kk * 32);
        fa[2] = *(const bf16x8*)(Fb2 + kk * 32);
        fa[3] = *(const bf16x8*)(Fb3 + kk * 32);
        bf16x8 sbv[4];
#pragma unroll
        for (int n = 0; n < 4; ++n) {
            int bt = n * 16 + lr;
            int L = bt * 512 + kk * 64 + lg * 16;
            sbv[n] = *(const bf16x8*)(skb + (L ^ ((bt & 7) << 4)));
        }
#pragma unroll
        for (int m = 0; m < 4; ++m)
#pragma unroll
            for (int n = 0; n < 4; ++n)
                acc2[m][n] = __builtin_amdgcn_mfma_f32_16x16x32_bf16(fa[m], sbv[n], acc2[m][n], 0, 0, 0);
    }

    int b = bt0 >> 15;
    int t0 = bt0 & (T_LEN - 1);
#pragma unroll
    for (int m = 0; m < 4; ++m) {
        int o0 = ocb + m * 16 + lg * 4;
        float q0 = bfv[o0], q1 = bfv[o0 + 1], q2 = bfv[o0 + 2], q3 = bfv[o0 + 3];
#pragma unroll
        for (int n = 0; n < 4; ++n) {
            int t = t0 + n * 16 + lr;
            f32x4 v = acc2[m][n];
            outp[((size_t)(b * OUTC + o0 + 0) << 15) + t] = v[0] + q0;
            outp[((size_t)(b * OUTC + o0 + 1) << 15) + t] = v[1] + q1;
            outp[((size_t)(b * OUTC + o0 + 2) << 15) + t] = v[2] + q2;
            outp[((size_t)(b * OUTC + o0 + 3) << 15) + t] = v[3] + q3;
        }
    }
}

extern "C" void kernel_launch(void* const* d_in, const int* in_sizes, int n_in,
                              void* d_out, int out_size, void* d_ws, size_t ws_size,
                              hipStream_t stream) {
    const float* x       = (const float*)d_in[0];
    const float* W_start = (const float*)d_in[1];
    const float* b_start = (const float*)d_in[2];
    const float* Wd      = (const float*)d_in[3];
    const float* bd      = (const float*)d_in[4];
    const float* Wr      = (const float*)d_in[5];
    const float* br      = (const float*)d_in[6];
    const float* Ws      = (const float*)d_in[7];
    const float* bs      = (const float*)d_in[8];
    const float* Wf      = (const float*)d_in[9];
    const float* bfv     = (const float*)d_in[10];

    char* wsb = (char*)d_ws;
    unsigned short* Wsk  = (unsigned short*)(wsb);                      // 655360 B
    unsigned short* Wfk  = (unsigned short*)(wsb + 655360);             // 131072 B
    unsigned short* Wd1k = (unsigned short*)(wsb + 786432);             // 81920 B
    unsigned short* Wd0k = (unsigned short*)(wsb + 868352);             // 81920 B
    unsigned short* Wrk  = (unsigned short*)(wsb + 950272);             // 81920 B
    float*          bs_sum = (float*)(wsb + 1032192);                   // 1024 B
    char* S1 = wsb + (1 << 20);            // stream slots 1..40 (= hist layers 0..39)
    char* X  = S1 + 40 * SLOTB;            // slot 0

    auto slotptr = [&](int i) -> unsigned short* {
        return (unsigned short*)(i == 0 ? X : S1 + (size_t)(i - 1) * SLOTB);
    };

    k_prep<<<(SC * KTOT + OUTC * SC + 3 * NL * 1024 + SC + 255) / 256, 256, 0, stream>>>(
        Ws, Wf, Wd, Wr, bs, Wsk, Wfk, Wd1k, Wd0k, Wrk, bs_sum);
    k_start<<<NBT / 256, 256, 0, stream>>>(x, W_start, b_start, slotptr(0));

    for (int i = 0; i < NL; ++i) {
        int d = 1 << (i % 10);
        k_layer<<<NBT / 128, 256, 0, stream>>>(slotptr(i), slotptr(i + 1),
                                               Wd1k + i * 1024, Wd0k + i * 1024, Wrk + i * 1024,
                                               bd + i * DC, br + i * RC, d);
    }

    k_skipfinal<<<NBT / 64, 256, 0, stream>>>((unsigned short*)S1, Wsk, Wfk, bs_sum, bfv, (float*)d_out);
}